// Round 6
// baseline (167.542 us; speedup 1.0000x reference)
//
#include <hip/hip_runtime.h>
#include <cstdint>
#include <cstddef>

#define HID    256
#define NROW   1024          // 4*HID gate rows
#define KSTEPS 7
#define ZM     64
#define BATCH  32768
#define WMSZ   (BATCH * ZM)  // floats per (which,m) output slab = 2097152

typedef float f32x4 __attribute__((ext_vector_type(4)));

// ---- workspace layout (float offsets) ----
#define WS_GATES 0                          // 6 buffers of NROW (pre-activation gates)
#define WS_C     (6 * NROW)                 // c_s at s*HID (slot 0 unused, c_0 == 0)
#define WS_TAB   (6 * NROW + 7 * HID)       // 896 projection table [which][m][j]
#define WS_WSUM  (6 * NROW + 7 * HID + 896) // 1024x256 = W_ih + W_hh

// fast, NaN-free for the gate range we see (|x| < ~6)
__device__ __forceinline__ float sigf(float x)       { return 1.0f / (1.0f + __expf(-x)); }
__device__ __forceinline__ float tanhf_fast(float x) { return 1.0f - 2.0f / (__expf(2.0f * x) + 1.0f); }

__device__ __forceinline__ float dot4(f32x4 a, f32x4 b) {
    return a.x * b.x + a.y * b.y + a.z * b.z + a.w * b.w;
}

// broadcast one (which,m) slab chunk: 256 threads, 16 nontemporal float4 stores each
__device__ __forceinline__ void bcast_wm(const float* __restrict__ tab,
                                         f32x4* __restrict__ out,
                                         int wm, int chunk, int t) {
    const f32x4* t4 = (const f32x4*)tab;
    const f32x4 v = t4[wm * 16 + (t & 15)];
    size_t base = (size_t)wm * (WMSZ / 4) + (size_t)chunk * 4096 + t;
    #pragma unroll
    for (int k = 0; k < 16; ++k)
        __builtin_nontemporal_store(v, &out[base + (size_t)k * 256]);
}

// project one 64-wide row: tab[wm*64+j] = W[j,:].p + b[j]; 256 threads, 4 per j
__device__ __forceinline__ void project_row(const float* __restrict__ W,
                                            const float* __restrict__ bvec,
                                            const float* p, float* __restrict__ tab,
                                            int wm, int t) {
    const int j = t >> 2, q = t & 3;
    const f32x4* w4 = (const f32x4*)(W + (size_t)j * HID);
    const f32x4* p4 = (const f32x4*)p;
    float acc = 0.f;
    #pragma unroll
    for (int kk = 0; kk < 16; ++kk) acc += dot4(w4[q * 16 + kk], p4[q * 16 + kk]);
    acc += __shfl_xor(acc, 1);
    acc += __shfl_xor(acc, 2);
    if (q == 0) tab[wm * ZM + j] = acc + bvec[j];
}

// ---- K0: gates0 = Wih.zm1 + bias (b<64); project m=0 (b=64,65); Wsum (b>=66) ----
__global__ __launch_bounds__(256) void k_init(
    const float* __restrict__ zm1,
    const float* __restrict__ Wih, const float* __restrict__ Whh,
    const float* __restrict__ bih, const float* __restrict__ bhh,
    const float* __restrict__ Wloc, const float* __restrict__ bloc,
    const float* __restrict__ Wsc,  const float* __restrict__ bsc,
    float* __restrict__ ws)
{
    const int t = threadIdx.x, b = blockIdx.x;
    if (b < 64) {
        const int row = b * 16 + (t >> 4);
        const int l16 = t & 15;
        const f32x4* w4 = (const f32x4*)(Wih + (size_t)row * HID);
        const f32x4* x4 = (const f32x4*)zm1;
        float part = 0.f;
        #pragma unroll
        for (int kk = 0; kk < 4; ++kk) part += dot4(w4[l16 * 4 + kk], x4[l16 * 4 + kk]);
        part += __shfl_xor(part, 1);
        part += __shfl_xor(part, 2);
        part += __shfl_xor(part, 4);
        part += __shfl_xor(part, 8);
        if (l16 == 0) ws[WS_GATES + row] = part + bih[row] + bhh[row];
    } else if (b < 66) {
        const int which = b - 64;
        project_row(which ? Wsc : Wloc, which ? bsc : bloc, zm1,
                    ws + WS_TAB, which * KSTEPS + 0, t);
    } else {
        const int id = (b - 66) * 256 + t;   // 0..65535 f32x4 of the 1 MB matrix
        ((f32x4*)(ws + WS_WSUM))[id] = ((const f32x4*)Wih)[id] + ((const f32x4*)Whh)[id];
    }
}

// ---- K_s (s=1..5): h_s + gates_s (b<64); project m=s (b=64,65); bcast m=s-1 (b>=66) ----
__global__ __launch_bounds__(256) void k_step(
    const float* __restrict__ bih, const float* __restrict__ bhh,
    const float* __restrict__ Wloc, const float* __restrict__ bloc,
    const float* __restrict__ Wsc,  const float* __restrict__ bsc,
    float* __restrict__ ws, f32x4* __restrict__ out, int s)
{
    __shared__ float hsh[HID];
    const int t = threadIdx.x, b = blockIdx.x;
    if (b < 66) {
        const float* gp = ws + WS_GATES + (size_t)(s - 1) * NROW;
        float gi = gp[t], gf = gp[HID + t], gg = gp[2 * HID + t], go = gp[3 * HID + t];
        float cp = (s == 1) ? 0.f : ws[WS_C + (size_t)(s - 1) * HID + t];
        float cn = sigf(gf) * cp + sigf(gi) * tanhf_fast(gg);
        float h  = sigf(go) * tanhf_fast(cn);
        if (b == 0) ws[WS_C + (size_t)s * HID + t] = cn;
        hsh[t] = h;
        __syncthreads();
        if (b < 64) {
            const int row = b * 16 + (t >> 4);
            const int l16 = t & 15;
            const f32x4* w4 = (const f32x4*)(ws + WS_WSUM + (size_t)row * HID);
            const f32x4* h4 = (const f32x4*)hsh;
            float part = 0.f;
            #pragma unroll
            for (int kk = 0; kk < 4; ++kk) part += dot4(w4[l16 * 4 + kk], h4[l16 * 4 + kk]);
            part += __shfl_xor(part, 1);
            part += __shfl_xor(part, 2);
            part += __shfl_xor(part, 4);
            part += __shfl_xor(part, 8);
            if (l16 == 0) ws[WS_GATES + (size_t)s * NROW + row] = part + bih[row] + bhh[row];
        } else {
            const int which = b - 64;
            project_row(which ? Wsc : Wloc, which ? bsc : bloc, hsh,
                        ws + WS_TAB, which * KSTEPS + s, t);
        }
    } else {
        const int bb = b - 66;                       // 0..255
        const int wm = (bb >> 7) * KSTEPS + (s - 1); // which = bb>>7
        bcast_wm(ws + WS_TAB, out, wm, bb & 127, t);
    }
}

// ---- K6: h_6 + project m=6 (b=0,1); bcast m=5 (b>=2) ----
__global__ __launch_bounds__(256) void k_six(
    const float* __restrict__ Wloc, const float* __restrict__ bloc,
    const float* __restrict__ Wsc,  const float* __restrict__ bsc,
    float* __restrict__ ws, f32x4* __restrict__ out)
{
    __shared__ float hsh[HID];
    const int t = threadIdx.x, b = blockIdx.x;
    if (b < 2) {
        const float* gp = ws + WS_GATES + (size_t)5 * NROW;
        float gi = gp[t], gf = gp[HID + t], gg = gp[2 * HID + t], go = gp[3 * HID + t];
        float cp = ws[WS_C + (size_t)5 * HID + t];
        float cn = sigf(gf) * cp + sigf(gi) * tanhf_fast(gg);
        hsh[t] = sigf(go) * tanhf_fast(cn);
        __syncthreads();
        const int which = b;
        project_row(which ? Wsc : Wloc, which ? bsc : bloc, hsh,
                    ws + WS_TAB, which * KSTEPS + 6, t);
    } else {
        const int bb = b - 2;
        const int wm = (bb >> 7) * KSTEPS + 5;
        bcast_wm(ws + WS_TAB, out, wm, bb & 127, t);
    }
}

// ---- K7: bcast m=6 (the only exposed broadcast, 16.8 MB) ----
__global__ __launch_bounds__(256) void k_bcast6(
    const float* __restrict__ tab, f32x4* __restrict__ out)
{
    const int b = blockIdx.x;                 // 0..255
    const int wm = (b >> 7) * KSTEPS + 6;
    bcast_wm(tab, out, wm, b & 127, threadIdx.x);
}

extern "C" void kernel_launch(void* const* d_in, const int* in_sizes, int n_in,
                              void* d_out, int out_size, void* d_ws, size_t ws_size,
                              hipStream_t stream) {
    const float* zm1  = (const float*)d_in[0];
    const float* Wih  = (const float*)d_in[1];
    const float* Whh  = (const float*)d_in[2];
    const float* bih  = (const float*)d_in[3];
    const float* bhh  = (const float*)d_in[4];
    const float* Wloc = (const float*)d_in[5];
    const float* bloc = (const float*)d_in[6];
    const float* Wsc  = (const float*)d_in[7];
    const float* bsc  = (const float*)d_in[8];
    float* ws = (float*)d_ws;
    f32x4* out = (f32x4*)d_out;

    k_init<<<322, 256, 0, stream>>>(zm1, Wih, Whh, bih, bhh, Wloc, bloc, Wsc, bsc, ws);
    for (int s = 1; s <= 5; ++s)
        k_step<<<322, 256, 0, stream>>>(bih, bhh, Wloc, bloc, Wsc, bsc, ws, out, s);
    k_six<<<258, 256, 0, stream>>>(Wloc, bloc, Wsc, bsc, ws, out);
    k_bcast6<<<256, 256, 0, stream>>>(ws + WS_TAB, out);
}